// Round 8
// baseline (507.734 us; speedup 1.0000x reference)
//
#include <hip/hip_runtime.h>

#define B_    4
#define N_    1024
#define FIN   128
#define FOUT  256
#define NH    8
#define ND    32
#define NSL   0.2f
#define LOG2E 1.44269504088896340736f

typedef _Float16 half8 __attribute__((ext_vector_type(8)));
typedef __fp16 fp16x2 __attribute__((ext_vector_type(2)));
typedef float f32x4 __attribute__((ext_vector_type(4)));

// ---- K0: bit-pack adj (int32 0/1) -> 1 bit/edge via wave ballot ----
__global__ __launch_bounds__(256) void gat_k0(
    const int* __restrict__ adj, unsigned long long* __restrict__ adjb64)
{
  const int gw = (blockIdx.x * 256 + threadIdx.x) >> 6;
  const int lane = threadIdx.x & 63;
  const size_t base0 = (size_t)gw * 1024;
#pragma unroll
  for (int it = 0; it < 16; ++it) {
    const size_t base = base0 + it * 64;
    const unsigned long long m = __ballot(adj[base + lane] != 0);
    if (lane == 0) adjb64[base >> 6] = m;
  }
}

// ---- K1: g16T[hb][f][n] = f16(h@W); elt/ert = LOG2E*(g.a_l / g.a_r) ----
// reps>1 only for profiling launches (identical idempotent work per rep).
__global__ __launch_bounds__(256) void gat_k1(
    const float* __restrict__ h, const float* __restrict__ W,
    const float* __restrict__ a_vec, _Float16* __restrict__ g16,
    float* __restrict__ elt, float* __restrict__ ert, int reps)
{
  __shared__ float hs[16][FIN];
  const int t = threadIdx.x;
  const int row0 = blockIdx.x * 16;

#pragma unroll 1
  for (int rep = 0; rep < reps; ++rep) {
    asm volatile("" ::: "memory");   // force real reloads each rep
    {
      const float4* src = (const float4*)(h + (size_t)row0 * FIN);
      float4* dst = (float4*)&hs[0][0];
      dst[t]       = src[t];
      dst[t + 256] = src[t + 256];
    }
    __syncthreads();

    const int cp = t & 127;
    const int c0 = 2 * cp;
    const int r0 = (t >> 7) * 8;
    float acc0[8] = {0.f,0.f,0.f,0.f,0.f,0.f,0.f,0.f};
    float acc1[8] = {0.f,0.f,0.f,0.f,0.f,0.f,0.f,0.f};

#pragma unroll 4
    for (int k4 = 0; k4 < FIN; k4 += 4) {
      const float2 w0 = *(const float2*)&W[(k4 + 0) * FOUT + c0];
      const float2 w1 = *(const float2*)&W[(k4 + 1) * FOUT + c0];
      const float2 w2 = *(const float2*)&W[(k4 + 2) * FOUT + c0];
      const float2 w3 = *(const float2*)&W[(k4 + 3) * FOUT + c0];
#pragma unroll
      for (int r = 0; r < 8; ++r) {
        const float4 hv = *(const float4*)&hs[r0 + r][k4];
        acc0[r] += hv.x * w0.x + hv.y * w1.x + hv.z * w2.x + hv.w * w3.x;
        acc1[r] += hv.x * w0.y + hv.y * w1.y + hv.z * w2.y + hv.w * w3.y;
      }
    }

    const int f0 = c0 & 31, head = c0 >> 5;
    const int b = row0 >> 10, n0 = row0 & 1023;
    const int hb = b * NH + head;

    half8 hv0, hv1;
#pragma unroll
    for (int r = 0; r < 8; ++r) { hv0[r] = (_Float16)acc0[r]; hv1[r] = (_Float16)acc1[r]; }
    *(half8*)&g16[((size_t)hb * ND + f0) * N_ + n0 + r0]     = hv0;
    *(half8*)&g16[((size_t)hb * ND + f0 + 1) * N_ + n0 + r0] = hv1;

    const float al0 = a_vec[f0] * LOG2E,      al1 = a_vec[f0 + 1] * LOG2E;
    const float ar0 = a_vec[ND + f0] * LOG2E, ar1 = a_vec[ND + f0 + 1] * LOG2E;
#pragma unroll
    for (int r = 0; r < 8; ++r) {
      float pl = acc0[r] * al0 + acc1[r] * al1;
      float pr = acc0[r] * ar0 + acc1[r] * ar1;
#pragma unroll
      for (int m = 8; m >= 1; m >>= 1) {
        pl += __shfl_xor(pl, m, 16);
        pr += __shfl_xor(pr, m, 16);
      }
      if ((t & 15) == 0) {
        elt[(size_t)hb * N_ + n0 + r0 + r] = pl;
        ert[(size_t)hb * N_ + n0 + r0 + r] = pr;
      }
    }
    __syncthreads();
  }
}

#define COMPUTE4(G0v, G1v, AW, KB)                                              \
  _Pragma("unroll")                                                             \
  for (int u = 0; u < 4; ++u) {                                                 \
    const unsigned word = ((const unsigned*)&(AW))[u];                          \
    const unsigned wsh = word >> (kg * 8);                                      \
    const int ks = wv * 256 + (KB) + u * 32 + kg * 8;                           \
    const float4 e0 = *(const float4*)&er_s[ks];                                \
    const float4 e1 = *(const float4*)&er_s[ks + 4];                            \
    const float er8[8] = {e0.x, e0.y, e0.z, e0.w, e1.x, e1.y, e1.z, e1.w};      \
    float pv[8];                                                                \
    _Pragma("unroll")                                                           \
    for (int e = 0; e < 8; ++e) {                                               \
      float x = el_i + er8[e];                                                  \
      x = fmaxf(x, NSL * x);                                                    \
      float p;                                                                  \
      asm("v_exp_f32 %0, %1" : "=v"(p) : "v"(x));                               \
      pv[e] = ((wsh >> e) & 1u) ? p : 0.f;                                      \
    }                                                                           \
    union { half8 h8; unsigned uu[4]; } P;                                      \
    _Pragma("unroll")                                                           \
    for (int q = 0; q < 4; ++q) {                                               \
      union { fp16x2 hh; unsigned uu; } cv;                                     \
      cv.hh = __builtin_amdgcn_cvt_pkrtz(pv[2 * q], pv[2 * q + 1]);             \
      P.uu[q] = cv.uu;                                                          \
    }                                                                           \
    acc0 = __builtin_amdgcn_mfma_f32_16x16x32_f16(G0v[u], P.h8, acc0, 0, 0, 0); \
    acc1 = __builtin_amdgcn_mfma_f32_16x16x32_f16(G1v[u], P.h8, acc1, 0, 0, 0); \
    accd = __builtin_amdgcn_mfma_f32_16x16x32_f16(ones, P.h8, accd, 0, 0, 0);   \
  }

// ---- K3: bitmask adj + XCD swizzle; reps>1 only for profiling ----
__global__ __launch_bounds__(256, 3) void gat_k3(
    const unsigned* __restrict__ adjb, const _Float16* __restrict__ g16,
    const float* __restrict__ elt, const float* __restrict__ ert,
    float* __restrict__ out, int reps)
{
  __shared__ float er_s[N_];
  __shared__ float dpart[4][32][17];
  __shared__ float denp[4][16];

  const int t = threadIdx.x;
  const int u0 = blockIdx.x;
  const int v  = ((u0 & 7) << 8) | (u0 >> 3);   // XCD swizzle
  const int it   = v & 63;
  const int head = (v >> 6) & 7;
  const int b    = v >> 9;
  const int i0   = it * 16;
  const int hb   = b * NH + head;

  const int wv = t >> 6, lane = t & 63;
  const int li = lane & 15, kg = lane >> 4;

#pragma unroll 1
  for (int rep = 0; rep < reps; ++rep) {
    asm volatile("" ::: "memory");
    *(float4*)&er_s[4 * t] = *(const float4*)&ert[(size_t)hb * N_ + 4 * t];
    __syncthreads();

    const float el_i = elt[(size_t)hb * N_ + i0 + li];
    const int4* __restrict__ abase =
        (const int4*)(adjb + ((size_t)(b * N_ + i0 + li)) * 32 + wv * 8);
    const _Float16* __restrict__ arow0 =
        g16 + ((size_t)hb * ND + li) * N_ + wv * 256 + kg * 8;
    const _Float16* __restrict__ arow1 = arow0 + (size_t)16 * N_;

    f32x4 acc0 = {0.f, 0.f, 0.f, 0.f};
    f32x4 acc1 = {0.f, 0.f, 0.f, 0.f};
    f32x4 accd = {0.f, 0.f, 0.f, 0.f};
    const half8 ones = {(_Float16)1.f, (_Float16)1.f, (_Float16)1.f, (_Float16)1.f,
                        (_Float16)1.f, (_Float16)1.f, (_Float16)1.f, (_Float16)1.f};

    const int4 AWa = abase[0];
    const int4 AWb = abase[1];
    half8 Ga0[4], Ga1[4], Gb0[4], Gb1[4];
#pragma unroll
    for (int uq = 0; uq < 4; ++uq) {
      Ga0[uq] = *(const half8*)(arow0 + uq * 32);
      Ga1[uq] = *(const half8*)(arow1 + uq * 32);
      Gb0[uq] = *(const half8*)(arow0 + 128 + uq * 32);
      Gb1[uq] = *(const half8*)(arow1 + 128 + uq * 32);
    }

    COMPUTE4(Ga0, Ga1, AWa, 0)
    COMPUTE4(Gb0, Gb1, AWb, 128)

#pragma unroll
    for (int r = 0; r < 4; ++r) {
      dpart[wv][4 * kg + r][li]      = acc0[r];
      dpart[wv][16 + 4 * kg + r][li] = acc1[r];
    }
    if (lane < 16) denp[wv][lane] = accd[0];
    __syncthreads();

    for (int o = t; o < 512; o += 256) {
      const int f = o & 31, ii = o >> 5;
      const float s  = dpart[0][f][ii] + dpart[1][f][ii]
                     + dpart[2][f][ii] + dpart[3][f][ii];
      const float dn = denp[0][ii] + denp[1][ii] + denp[2][ii] + denp[3][ii];
      float w = s / dn;
      w = fmaxf(w, NSL * w);
      out[((size_t)(b * N_ + i0 + ii)) * FOUT + head * ND + f] = w;
    }
    __syncthreads();
  }
}

extern "C" void kernel_launch(void* const* d_in, const int* in_sizes, int n_in,
                              void* d_out, int out_size, void* d_ws, size_t ws_size,
                              hipStream_t stream) {
  const float* h     = (const float*)d_in[0];
  const int*   adj   = (const int*)d_in[1];
  const float* W     = (const float*)d_in[2];
  const float* a_vec = (const float*)d_in[3];
  float* out = (float*)d_out;

  _Float16* g16 = (_Float16*)d_ws;
  float* elt = (float*)(g16 + (size_t)B_ * NH * ND * N_);
  float* ert = elt + (size_t)B_ * NH * N_;
  unsigned long long* adjb64 = (unsigned long long*)(ert + (size_t)B_ * NH * N_);

  // real pipeline
  gat_k0<<<1024, 256, 0, stream>>>(adj, adjb64);
  gat_k1<<<(B_ * N_) / 16, 256, 0, stream>>>(h, W, a_vec, g16, elt, ert, 1);
  gat_k3<<<B_ * NH * (N_ / 16), 256, 0, stream>>>((const unsigned*)adjb64, g16, elt, ert, out, 1);

  // PROFILING launches (reps=16 -> >40us, visible in rocprof top-5 with counters;
  // idempotent identical work, removed next round)
  gat_k1<<<(B_ * N_) / 16, 256, 0, stream>>>(h, W, a_vec, g16, elt, ert, 16);
  gat_k3<<<B_ * NH * (N_ / 16), 256, 0, stream>>>((const unsigned*)adjb64, g16, elt, ert, out, 16);
}

// Round 9
// 297.437 us; speedup vs baseline: 1.7070x; 1.7070x over previous
//
#include <hip/hip_runtime.h>

#define B_    4
#define N_    1024
#define FIN   128
#define FOUT  256
#define NH    8
#define ND    32
#define NSL   0.2f
#define LOG2E 1.44269504088896340736f

typedef _Float16 half8 __attribute__((ext_vector_type(8)));
typedef __fp16 fp16x2 __attribute__((ext_vector_type(2)));
typedef float f32x4 __attribute__((ext_vector_type(4)));

// ---- K0: bit-pack adj -> 1 bit/edge via wave ballot ----
__global__ __launch_bounds__(256) void gat_k0(
    const int* __restrict__ adj, unsigned long long* __restrict__ adjb64)
{
  const int gw = (blockIdx.x * 256 + threadIdx.x) >> 6;
  const int lane = threadIdx.x & 63;
  const size_t base0 = (size_t)gw * 1024;
#pragma unroll
  for (int it = 0; it < 16; ++it) {
    const size_t base = base0 + it * 64;
    const unsigned long long m = __ballot(adj[base + lane] != 0);
    if (lane == 0) adjb64[base >> 6] = m;
  }
}

// ---- K0b: h -> f16 [4096][128]; W -> W^T f16 [256][128] ----
__global__ __launch_bounds__(256) void gat_k0b(
    const float* __restrict__ h, const float* __restrict__ W,
    _Float16* __restrict__ h16, _Float16* __restrict__ wt16)
{
  const int t = threadIdx.x;
  if (blockIdx.x < 256) {
    const size_t base = (size_t)blockIdx.x * 2048 + t * 8;
    const float4 v0 = *(const float4*)(h + base);
    const float4 v1 = *(const float4*)(h + base + 4);
    half8 o;
    o[0]=(_Float16)v0.x; o[1]=(_Float16)v0.y; o[2]=(_Float16)v0.z; o[3]=(_Float16)v0.w;
    o[4]=(_Float16)v1.x; o[5]=(_Float16)v1.y; o[6]=(_Float16)v1.z; o[7]=(_Float16)v1.w;
    *(half8*)(h16 + base) = o;
  } else {
    const int f  = (blockIdx.x - 256) * 16 + (t >> 4);
    const int k0 = (t & 15) * 8;
    half8 o;
#pragma unroll
    for (int e = 0; e < 8; ++e) o[e] = (_Float16)W[(size_t)(k0 + e) * FOUT + f];
    *(half8*)(wt16 + (size_t)f * FIN + k0) = o;
  }
}

// ---- K1m: g = h@W via MFMA. D[f][n] == g16T layout directly.
// el/er partials from the same accumulators -> atomicAdd into zeroed elt/ert.
__global__ __launch_bounds__(256) void gat_k1m(
    const _Float16* __restrict__ wt16, const _Float16* __restrict__ h16,
    const float* __restrict__ a_vec, _Float16* __restrict__ g16,
    float* __restrict__ elt, float* __restrict__ ert)
{
  const int t = threadIdx.x;
  const int fq = blockIdx.x & 3;
  const int nt = blockIdx.x >> 2;          // 0..255
  const int wv = t >> 6, lane = t & 63;
  const int li = lane & 15, kg = lane >> 4;
  const int fbase = fq * 64 + wv * 16;     // 16 f-rows per wave
  const int n0 = nt * 16;
  const int b = n0 >> 10, nn = n0 & 1023;
  const int head = fbase >> 5;
  const int hb = b * NH + head;
  const int fi0 = fbase & 31;

  const _Float16* __restrict__ arow = wt16 + (size_t)(fbase + li) * FIN + kg * 8;
  const _Float16* __restrict__ brow = h16 + (size_t)(n0 + li) * FIN + kg * 8;

  f32x4 acc = {0.f, 0.f, 0.f, 0.f};
#pragma unroll
  for (int ks = 0; ks < 4; ++ks) {
    const half8 Af = *(const half8*)(arow + ks * 32);
    const half8 Bf = *(const half8*)(brow + ks * 32);
    acc = __builtin_amdgcn_mfma_f32_16x16x32_f16(Af, Bf, acc, 0, 0, 0);
  }

  float pl = 0.f, pr = 0.f;
#pragma unroll
  for (int r = 0; r < 4; ++r) {
    const int fi = fi0 + kg * 4 + r;
    g16[((size_t)hb * ND + fi) * N_ + nn + li] = (_Float16)acc[r];
    pl += a_vec[fi] * acc[r];
    pr += a_vec[ND + fi] * acc[r];
  }
  pl *= LOG2E; pr *= LOG2E;
  pl += __shfl_xor(pl, 16); pl += __shfl_xor(pl, 32);
  pr += __shfl_xor(pr, 16); pr += __shfl_xor(pr, 32);
  if (lane < 16) {
    atomicAdd(&elt[(size_t)hb * N_ + nn + li], pl);
    atomicAdd(&ert[(size_t)hb * N_ + nn + li], pr);
  }
}

// ---- K3: block=(b,head,32-i tile); wave: 32 i x 32 f x 256 j.
// i-pairing reuses each Ag for 2 P-tiles -> g16 L2 traffic halved.
// ABL=1: exp->mul (profiling-only ablation, writes scratch).
template<int ABL>
__global__ __launch_bounds__(256) void gat_k3(
    const unsigned* __restrict__ adjb, const _Float16* __restrict__ g16,
    const float* __restrict__ elt, const float* __restrict__ ert,
    float* __restrict__ out, int reps)
{
  __shared__ float er_s[N_];
  __shared__ float dpart[4][32][34];
  __shared__ float denp[4][32];

  const int t = threadIdx.x;
  const int u0 = blockIdx.x;
  const int v  = ((u0 & 7) << 7) | (u0 >> 3);   // XCD swizzle (1024 = 8*128)
  const int it   = v & 31;
  const int head = (v >> 5) & 7;
  const int b    = v >> 8;
  const int i0   = it * 32;
  const int hb   = b * NH + head;

  const int wv = t >> 6, lane = t & 63;
  const int li = lane & 15, kg = lane >> 4;

#pragma unroll 1
  for (int rep = 0; rep < reps; ++rep) {
    asm volatile("" ::: "memory");
    *(float4*)&er_s[4 * t] = *(const float4*)&ert[(size_t)hb * N_ + 4 * t];
    __syncthreads();

    const float el_a = elt[(size_t)hb * N_ + i0 + li];
    const float el_b = elt[(size_t)hb * N_ + i0 + 16 + li];
    const int4* __restrict__ abA =
        (const int4*)(adjb + ((size_t)(b * N_ + i0 + li)) * 32) + wv * 2;
    const int4* __restrict__ abB =
        (const int4*)(adjb + ((size_t)(b * N_ + i0 + 16 + li)) * 32) + wv * 2;
    const _Float16* __restrict__ arow0 =
        g16 + ((size_t)hb * ND + li) * N_ + wv * 256 + kg * 8;
    const _Float16* __restrict__ arow1 = arow0 + (size_t)16 * N_;

    f32x4 acc0 = {0,0,0,0}, acc1 = {0,0,0,0}, accd = {0,0,0,0};
    f32x4 acc0b = {0,0,0,0}, acc1b = {0,0,0,0}, accdb = {0,0,0,0};
    const half8 ones = {(_Float16)1.f, (_Float16)1.f, (_Float16)1.f, (_Float16)1.f,
                        (_Float16)1.f, (_Float16)1.f, (_Float16)1.f, (_Float16)1.f};

    const int4 A0 = abA[0], A1 = abA[1];
    const int4 B0 = abB[0], B1 = abB[1];
    const unsigned wA[8] = {(unsigned)A0.x,(unsigned)A0.y,(unsigned)A0.z,(unsigned)A0.w,
                            (unsigned)A1.x,(unsigned)A1.y,(unsigned)A1.z,(unsigned)A1.w};
    const unsigned wB[8] = {(unsigned)B0.x,(unsigned)B0.y,(unsigned)B0.z,(unsigned)B0.w,
                            (unsigned)B1.x,(unsigned)B1.y,(unsigned)B1.z,(unsigned)B1.w};

#pragma unroll
    for (int u = 0; u < 8; ++u) {
      const half8 Ag0 = *(const half8*)(arow0 + u * 32);
      const half8 Ag1 = *(const half8*)(arow1 + u * 32);
      const int ks = wv * 256 + u * 32 + kg * 8;
      const float4 e0 = *(const float4*)&er_s[ks];
      const float4 e1 = *(const float4*)&er_s[ks + 4];
      const float er8[8] = {e0.x, e0.y, e0.z, e0.w, e1.x, e1.y, e1.z, e1.w};
      const unsigned sA = wA[u] >> (kg * 8);
      const unsigned sB = wB[u] >> (kg * 8);

      float pva[8], pvb[8];
#pragma unroll
      for (int e = 0; e < 8; ++e) {
        float xa = el_a + er8[e];
        float xb = el_b + er8[e];
        xa = fmaxf(xa, NSL * xa);
        xb = fmaxf(xb, NSL * xb);
        float pa, pb;
        if (ABL == 0) {
          asm("v_exp_f32 %0, %1" : "=v"(pa) : "v"(xa));
          asm("v_exp_f32 %0, %1" : "=v"(pb) : "v"(xb));
        } else {
          asm("v_mul_f32 %0, %1, %1" : "=v"(pa) : "v"(xa));
          asm("v_mul_f32 %0, %1, %1" : "=v"(pb) : "v"(xb));
        }
        pva[e] = ((sA >> e) & 1u) ? pa : 0.f;
        pvb[e] = ((sB >> e) & 1u) ? pb : 0.f;
      }

      union { half8 h8; unsigned uu[4]; } PA, PB;
#pragma unroll
      for (int q = 0; q < 4; ++q) {
        union { fp16x2 hh; unsigned uu; } c1, c2;
        c1.hh = __builtin_amdgcn_cvt_pkrtz(pva[2*q], pva[2*q+1]);
        c2.hh = __builtin_amdgcn_cvt_pkrtz(pvb[2*q], pvb[2*q+1]);
        PA.uu[q] = c1.uu; PB.uu[q] = c2.uu;
      }

      acc0  = __builtin_amdgcn_mfma_f32_16x16x32_f16(Ag0, PA.h8, acc0, 0, 0, 0);
      acc1  = __builtin_amdgcn_mfma_f32_16x16x32_f16(Ag1, PA.h8, acc1, 0, 0, 0);
      accd  = __builtin_amdgcn_mfma_f32_16x16x32_f16(ones, PA.h8, accd, 0, 0, 0);
      acc0b = __builtin_amdgcn_mfma_f32_16x16x32_f16(Ag0, PB.h8, acc0b, 0, 0, 0);
      acc1b = __builtin_amdgcn_mfma_f32_16x16x32_f16(Ag1, PB.h8, acc1b, 0, 0, 0);
      accdb = __builtin_amdgcn_mfma_f32_16x16x32_f16(ones, PB.h8, accdb, 0, 0, 0);
    }

#pragma unroll
    for (int r = 0; r < 4; ++r) {
      dpart[wv][4*kg + r][li]           = acc0[r];
      dpart[wv][16 + 4*kg + r][li]      = acc1[r];
      dpart[wv][4*kg + r][16 + li]      = acc0b[r];
      dpart[wv][16 + 4*kg + r][16 + li] = acc1b[r];
    }
    if (lane < 16) { denp[wv][li] = accd[0]; denp[wv][16 + li] = accdb[0]; }
    __syncthreads();

    for (int o = t; o < 1024; o += 256) {
      const int f = o & 31, ii = o >> 5;
      const float s  = dpart[0][f][ii] + dpart[1][f][ii]
                     + dpart[2][f][ii] + dpart[3][f][ii];
      const float dn = denp[0][ii] + denp[1][ii] + denp[2][ii] + denp[3][ii];
      float w = s / dn;
      w = fmaxf(w, NSL * w);
      out[((size_t)(b * N_ + i0 + ii)) * FOUT + head * ND + f] = w;
    }
    __syncthreads();
  }
}

extern "C" void kernel_launch(void* const* d_in, const int* in_sizes, int n_in,
                              void* d_out, int out_size, void* d_ws, size_t ws_size,
                              hipStream_t stream) {
  const float* h     = (const float*)d_in[0];
  const int*   adj   = (const int*)d_in[1];
  const float* W     = (const float*)d_in[2];
  const float* a_vec = (const float*)d_in[3];
  float* out = (float*)d_out;

  char* ws = (char*)d_ws;
  _Float16* g16  = (_Float16*)(ws);                       // 2 MB
  float*    elt  = (float*)(ws + (2u << 20));             // 128 KB
  float*    ert  = (float*)(ws + (2u << 20) + (128u << 10));
  unsigned long long* adjb64 = (unsigned long long*)(ws + (2304u << 10)); // 512 KB
  _Float16* h16  = (_Float16*)(ws + (2816u << 10));       // 1 MB
  _Float16* wt16 = (_Float16*)(ws + (3840u << 10));       // 64 KB
  float*    sout = (float*)(ws + (8u << 20));             // 16 MB scratch (prof)

  hipMemsetAsync(elt, 0, 2 * (size_t)B_ * NH * N_ * sizeof(float), stream);
  gat_k0<<<1024, 256, 0, stream>>>(adj, adjb64);
  gat_k0b<<<272, 256, 0, stream>>>(h, W, h16, wt16);
  gat_k1m<<<1024, 256, 0, stream>>>(wt16, h16, a_vec, g16, elt, ert);
  gat_k3<0><<<1024, 256, 0, stream>>>((const unsigned*)adjb64, g16, elt, ert, out, 1);

  // PROFILING (scratch out; removed for production): within-run A/B exp vs mul
  gat_k3<0><<<1024, 256, 0, stream>>>((const unsigned*)adjb64, g16, elt, ert, sout, 12);
  gat_k3<1><<<1024, 256, 0, stream>>>((const unsigned*)adjb64, g16, elt, ert, sout, 12);
}

// Round 10
// 39.112 us; speedup vs baseline: 12.9814x; 7.6047x over previous
//
#include <hip/hip_runtime.h>

#define B_    4
#define N_    1024
#define FIN   128
#define FOUT  256
#define NH    8
#define ND    32
#define NSL   0.2f
#define LOG2E 1.44269504088896340736f

typedef _Float16 half8 __attribute__((ext_vector_type(8)));
typedef __fp16 fp16x2 __attribute__((ext_vector_type(2)));
typedef float f32x4 __attribute__((ext_vector_type(4)));

// ---- K0: bit-pack adj -> 1 bit/edge via wave ballot ----
__global__ __launch_bounds__(256) void gat_k0(
    const int* __restrict__ adj, unsigned long long* __restrict__ adjb64)
{
  const int gw = (blockIdx.x * 256 + threadIdx.x) >> 6;
  const int lane = threadIdx.x & 63;
  const size_t base0 = (size_t)gw * 1024;
#pragma unroll
  for (int it = 0; it < 16; ++it) {
    const size_t base = base0 + it * 64;
    const unsigned long long m = __ballot(adj[base + lane] != 0);
    if (lane == 0) adjb64[base >> 6] = m;
  }
}

// ---- K0b: h -> f16 [4096][128]; W -> W^T f16 [256][128] ----
__global__ __launch_bounds__(256) void gat_k0b(
    const float* __restrict__ h, const float* __restrict__ W,
    _Float16* __restrict__ h16, _Float16* __restrict__ wt16)
{
  const int t = threadIdx.x;
  if (blockIdx.x < 256) {
    const size_t base = (size_t)blockIdx.x * 2048 + t * 8;
    const float4 v0 = *(const float4*)(h + base);
    const float4 v1 = *(const float4*)(h + base + 4);
    half8 o;
    o[0]=(_Float16)v0.x; o[1]=(_Float16)v0.y; o[2]=(_Float16)v0.z; o[3]=(_Float16)v0.w;
    o[4]=(_Float16)v1.x; o[5]=(_Float16)v1.y; o[6]=(_Float16)v1.z; o[7]=(_Float16)v1.w;
    *(half8*)(h16 + base) = o;
  } else {
    const int f  = (blockIdx.x - 256) * 16 + (t >> 4);
    const int k0 = (t & 15) * 8;
    half8 o;
#pragma unroll
    for (int e = 0; e < 8; ++e) o[e] = (_Float16)W[(size_t)(k0 + e) * FOUT + f];
    *(half8*)(wt16 + (size_t)f * FIN + k0) = o;
  }
}

// ---- K1m: g = h@W via MFMA; D[f][n] == g16T layout. el/er via shfl+atomicAdd. ----
__global__ __launch_bounds__(256) void gat_k1m(
    const _Float16* __restrict__ wt16, const _Float16* __restrict__ h16,
    const float* __restrict__ a_vec, _Float16* __restrict__ g16,
    float* __restrict__ elt, float* __restrict__ ert)
{
  const int t = threadIdx.x;
  const int fq = blockIdx.x & 3;
  const int nt = blockIdx.x >> 2;
  const int wv = t >> 6, lane = t & 63;
  const int li = lane & 15, kg = lane >> 4;
  const int fbase = fq * 64 + wv * 16;
  const int n0 = nt * 16;
  const int b = n0 >> 10, nn = n0 & 1023;
  const int head = fbase >> 5;
  const int hb = b * NH + head;
  const int fi0 = fbase & 31;

  const _Float16* __restrict__ arow = wt16 + (size_t)(fbase + li) * FIN + kg * 8;
  const _Float16* __restrict__ brow = h16 + (size_t)(n0 + li) * FIN + kg * 8;

  f32x4 acc = {0.f, 0.f, 0.f, 0.f};
#pragma unroll
  for (int ks = 0; ks < 4; ++ks) {
    const half8 Af = *(const half8*)(arow + ks * 32);
    const half8 Bf = *(const half8*)(brow + ks * 32);
    acc = __builtin_amdgcn_mfma_f32_16x16x32_f16(Af, Bf, acc, 0, 0, 0);
  }

  float pl = 0.f, pr = 0.f;
#pragma unroll
  for (int r = 0; r < 4; ++r) {
    const int fi = fi0 + kg * 4 + r;
    g16[((size_t)hb * ND + fi) * N_ + nn + li] = (_Float16)acc[r];
    pl += a_vec[fi] * acc[r];
    pr += a_vec[ND + fi] * acc[r];
  }
  pl *= LOG2E; pr *= LOG2E;
  pl += __shfl_xor(pl, 16); pl += __shfl_xor(pl, 32);
  pr += __shfl_xor(pr, 16); pr += __shfl_xor(pr, 32);
  if (lane < 16) {
    atomicAdd(&elt[(size_t)hb * N_ + nn + li], pl);
    atomicAdd(&ert[(size_t)hb * N_ + nn + li], pr);
  }
}

// ---- K3: block=(b,head,32-i tile), 512 thr / 8 waves; wave: 32 i x 32 f x 128 j.
// Same per-wave P-gen/MFMA structure as round 9 (verified), but 2x waves/CU to
// fill the 39% idle-bubble fraction (occupancy was the residue, not exp pipe).
__global__ __launch_bounds__(512) void gat_k3(
    const unsigned* __restrict__ adjb, const _Float16* __restrict__ g16,
    const float* __restrict__ elt, const float* __restrict__ ert,
    float* __restrict__ out)
{
  __shared__ float er_s[N_];
  __shared__ float dpart[8][32][34];
  __shared__ float denp[8][32];

  const int t = threadIdx.x;
  const int u0 = blockIdx.x;
  const int v  = ((u0 & 7) << 7) | (u0 >> 3);   // XCD swizzle (1024 = 8*128)
  const int it   = v & 31;
  const int head = (v >> 5) & 7;
  const int b    = v >> 8;
  const int i0   = it * 32;
  const int hb   = b * NH + head;

  const int wv = t >> 6, lane = t & 63;
  const int li = lane & 15, kg = lane >> 4;

  if (t < 256) *(float4*)&er_s[4 * t] = *(const float4*)&ert[(size_t)hb * N_ + 4 * t];
  __syncthreads();

  const float el_a = elt[(size_t)hb * N_ + i0 + li];
  const float el_b = elt[(size_t)hb * N_ + i0 + 16 + li];
  const int4* __restrict__ abA =
      (const int4*)(adjb + ((size_t)(b * N_ + i0 + li)) * 32) + wv;       // 128 j-bits
  const int4* __restrict__ abB =
      (const int4*)(adjb + ((size_t)(b * N_ + i0 + 16 + li)) * 32) + wv;
  const _Float16* __restrict__ arow0 =
      g16 + ((size_t)hb * ND + li) * N_ + wv * 128 + kg * 8;
  const _Float16* __restrict__ arow1 = arow0 + (size_t)16 * N_;

  f32x4 acc0 = {0,0,0,0}, acc1 = {0,0,0,0}, accd = {0,0,0,0};
  f32x4 acc0b = {0,0,0,0}, acc1b = {0,0,0,0}, accdb = {0,0,0,0};
  const half8 ones = {(_Float16)1.f, (_Float16)1.f, (_Float16)1.f, (_Float16)1.f,
                      (_Float16)1.f, (_Float16)1.f, (_Float16)1.f, (_Float16)1.f};

  const int4 A = abA[0];
  const int4 Bm = abB[0];
  const unsigned wA[4] = {(unsigned)A.x, (unsigned)A.y, (unsigned)A.z, (unsigned)A.w};
  const unsigned wB[4] = {(unsigned)Bm.x, (unsigned)Bm.y, (unsigned)Bm.z, (unsigned)Bm.w};

#pragma unroll
  for (int u = 0; u < 4; ++u) {
    const half8 Ag0 = *(const half8*)(arow0 + u * 32);
    const half8 Ag1 = *(const half8*)(arow1 + u * 32);
    const int ks = wv * 128 + u * 32 + kg * 8;
    const float4 e0 = *(const float4*)&er_s[ks];
    const float4 e1 = *(const float4*)&er_s[ks + 4];
    const float er8[8] = {e0.x, e0.y, e0.z, e0.w, e1.x, e1.y, e1.z, e1.w};
    const unsigned sA = wA[u] >> (kg * 8);
    const unsigned sB = wB[u] >> (kg * 8);

    float pva[8], pvb[8];
#pragma unroll
    for (int e = 0; e < 8; ++e) {
      float xa = el_a + er8[e];
      float xb = el_b + er8[e];
      xa = fmaxf(xa, NSL * xa);
      xb = fmaxf(xb, NSL * xb);
      float pa, pb;
      asm("v_exp_f32 %0, %1" : "=v"(pa) : "v"(xa));
      asm("v_exp_f32 %0, %1" : "=v"(pb) : "v"(xb));
      pva[e] = ((sA >> e) & 1u) ? pa : 0.f;
      pvb[e] = ((sB >> e) & 1u) ? pb : 0.f;
    }

    union { half8 h8; unsigned uu[4]; } PA, PB;
#pragma unroll
    for (int q = 0; q < 4; ++q) {
      union { fp16x2 hh; unsigned uu; } c1, c2;
      c1.hh = __builtin_amdgcn_cvt_pkrtz(pva[2*q], pva[2*q+1]);
      c2.hh = __builtin_amdgcn_cvt_pkrtz(pvb[2*q], pvb[2*q+1]);
      PA.uu[q] = c1.uu; PB.uu[q] = c2.uu;
    }

    acc0  = __builtin_amdgcn_mfma_f32_16x16x32_f16(Ag0, PA.h8, acc0, 0, 0, 0);
    acc1  = __builtin_amdgcn_mfma_f32_16x16x32_f16(Ag1, PA.h8, acc1, 0, 0, 0);
    accd  = __builtin_amdgcn_mfma_f32_16x16x32_f16(ones, PA.h8, accd, 0, 0, 0);
    acc0b = __builtin_amdgcn_mfma_f32_16x16x32_f16(Ag0, PB.h8, acc0b, 0, 0, 0);
    acc1b = __builtin_amdgcn_mfma_f32_16x16x32_f16(Ag1, PB.h8, acc1b, 0, 0, 0);
    accdb = __builtin_amdgcn_mfma_f32_16x16x32_f16(ones, PB.h8, accdb, 0, 0, 0);
  }

#pragma unroll
  for (int r = 0; r < 4; ++r) {
    dpart[wv][4*kg + r][li]           = acc0[r];
    dpart[wv][16 + 4*kg + r][li]      = acc1[r];
    dpart[wv][4*kg + r][16 + li]      = acc0b[r];
    dpart[wv][16 + 4*kg + r][16 + li] = acc1b[r];
  }
  if (lane < 16) { denp[wv][li] = accd[0]; denp[wv][16 + li] = accdb[0]; }
  __syncthreads();

  for (int o = t; o < 1024; o += 512) {
    const int f = o & 31, ii = o >> 5;
    float s = 0.f, dn = 0.f;
#pragma unroll
    for (int p = 0; p < 8; ++p) { s += dpart[p][f][ii]; dn += denp[p][ii]; }
    float w = s / dn;
    w = fmaxf(w, NSL * w);
    out[((size_t)(b * N_ + i0 + ii)) * FOUT + head * ND + f] = w;
  }
}

extern "C" void kernel_launch(void* const* d_in, const int* in_sizes, int n_in,
                              void* d_out, int out_size, void* d_ws, size_t ws_size,
                              hipStream_t stream) {
  const float* h     = (const float*)d_in[0];
  const int*   adj   = (const int*)d_in[1];
  const float* W     = (const float*)d_in[2];
  const float* a_vec = (const float*)d_in[3];
  float* out = (float*)d_out;

  char* ws = (char*)d_ws;
  _Float16* g16  = (_Float16*)(ws);                       // 2 MB
  float*    elt  = (float*)(ws + (2u << 20));             // 128 KB
  float*    ert  = (float*)(ws + (2u << 20) + (128u << 10));
  unsigned long long* adjb64 = (unsigned long long*)(ws + (2304u << 10)); // 512 KB
  _Float16* h16  = (_Float16*)(ws + (2816u << 10));       // 1 MB
  _Float16* wt16 = (_Float16*)(ws + (3840u << 10));       // 64 KB

  hipMemsetAsync(elt, 0, 2 * (size_t)B_ * NH * N_ * sizeof(float), stream);
  gat_k0<<<1024, 256, 0, stream>>>(adj, adjb64);
  gat_k0b<<<272, 256, 0, stream>>>(h, W, h16, wt16);
  gat_k1m<<<1024, 256, 0, stream>>>(wt16, h16, a_vec, g16, elt, ert);
  gat_k3<<<1024, 512, 0, stream>>>((const unsigned*)adjb64, g16, elt, ert, out);
}

// Round 11
// 33.281 us; speedup vs baseline: 15.2561x; 1.1752x over previous
//
#include <hip/hip_runtime.h>

#define B_    4
#define N_    1024
#define FIN   128
#define FOUT  256
#define NH    8
#define ND    32
#define NSL   0.2f
#define LOG2E 1.44269504088896340736f

typedef _Float16 half8 __attribute__((ext_vector_type(8)));
typedef __fp16 fp16x2 __attribute__((ext_vector_type(2)));
typedef float f32x4 __attribute__((ext_vector_type(4)));

// ---- kA: blocks 0..1023: bit-pack adj via ballot; 1024..1039: W -> W^T f16 ----
__global__ __launch_bounds__(256) void gat_kA(
    const int* __restrict__ adj, unsigned long long* __restrict__ adjb64,
    const float* __restrict__ W, _Float16* __restrict__ wt16)
{
  const int t = threadIdx.x;
  if (blockIdx.x < 1024) {
    const int gw = (blockIdx.x * 256 + t) >> 6;
    const int lane = t & 63;
    const size_t base0 = (size_t)gw * 1024;
#pragma unroll
    for (int it = 0; it < 16; ++it) {
      const size_t base = base0 + it * 64;
      const unsigned long long m = __ballot(adj[base + lane] != 0);
      if (lane == 0) adjb64[base >> 6] = m;
    }
  } else {
    const int f  = (blockIdx.x - 1024) * 16 + (t >> 4);
    const int k0 = (t & 15) * 8;
    half8 o;
#pragma unroll
    for (int e = 0; e < 8; ++e) o[e] = (_Float16)W[(size_t)(k0 + e) * FOUT + f];
    *(half8*)(wt16 + (size_t)f * FIN + k0) = o;
  }
}

// ---- kB: g = h@W via MFMA (h converted inline into LDS); el/er via LDS combine
// (one writer per element -> no atomics, no memset). D[f][n] == g16T layout.
__global__ __launch_bounds__(256) void gat_kB(
    const float* __restrict__ h, const _Float16* __restrict__ wt16,
    const float* __restrict__ a_vec, _Float16* __restrict__ g16,
    float* __restrict__ elt, float* __restrict__ ert)
{
  __shared__ _Float16 h16s[16][136];   // pad: 272B row stride, <=2-way on b128
  __shared__ float elp[4][16], erp[4][16];

  const int t = threadIdx.x;
  const int fq = blockIdx.x & 3;
  const int nt = blockIdx.x >> 2;
  const int n0 = nt * 16;
  const int b = n0 >> 10, nn = n0 & 1023;

  // stage h rows n0..n0+15, f32 -> f16
  {
    const int hr = t >> 4, hk = (t & 15) * 8;
    const float4 v0 = *(const float4*)&h[(size_t)(n0 + hr) * FIN + hk];
    const float4 v1 = *(const float4*)&h[(size_t)(n0 + hr) * FIN + hk + 4];
    half8 o;
    o[0]=(_Float16)v0.x; o[1]=(_Float16)v0.y; o[2]=(_Float16)v0.z; o[3]=(_Float16)v0.w;
    o[4]=(_Float16)v1.x; o[5]=(_Float16)v1.y; o[6]=(_Float16)v1.z; o[7]=(_Float16)v1.w;
    *(half8*)&h16s[hr][hk] = o;
  }
  __syncthreads();

  const int wv = t >> 6, lane = t & 63;
  const int li = lane & 15, kg = lane >> 4;
  const int fbase = fq * 64 + wv * 16;
  const int head  = fq * 2 + (wv >> 1);
  const int hb    = b * NH + head;
  const int fi0   = (wv & 1) * 16;

  const _Float16* __restrict__ arow = wt16 + (size_t)(fbase + li) * FIN + kg * 8;

  f32x4 acc = {0.f, 0.f, 0.f, 0.f};
#pragma unroll
  for (int ks = 0; ks < 4; ++ks) {
    const half8 Af = *(const half8*)(arow + ks * 32);
    const half8 Bf = *(const half8*)&h16s[li][ks * 32 + kg * 8];
    acc = __builtin_amdgcn_mfma_f32_16x16x32_f16(Af, Bf, acc, 0, 0, 0);
  }

  float pl = 0.f, pr = 0.f;
#pragma unroll
  for (int r = 0; r < 4; ++r) {
    const int fi = fi0 + kg * 4 + r;                   // within-head f, 0..31
    g16[((size_t)hb * ND + fi) * N_ + nn + li] = (_Float16)acc[r];
    pl += a_vec[fi] * acc[r];
    pr += a_vec[ND + fi] * acc[r];
  }
  pl *= LOG2E; pr *= LOG2E;
  pl += __shfl_xor(pl, 16); pl += __shfl_xor(pl, 32);
  pr += __shfl_xor(pr, 16); pr += __shfl_xor(pr, 32);
  if (lane < 16) { elp[wv][li] = pl; erp[wv][li] = pr; }
  __syncthreads();

  if (t < 32) {
    const int hh = t >> 4, ll = t & 15;
    const int hbw = b * NH + fq * 2 + hh;
    elt[(size_t)hbw * N_ + nn + ll] = elp[2 * hh][ll] + elp[2 * hh + 1][ll];
    ert[(size_t)hbw * N_ + nn + ll] = erp[2 * hh][ll] + erp[2 * hh + 1][ll];
  }
}

// ---- kC: block=(b,head,32-i tile), 512 thr / 8 waves; wave: 32 i x 32 f x 128 j ----
__global__ __launch_bounds__(512) void gat_kC(
    const unsigned* __restrict__ adjb, const _Float16* __restrict__ g16,
    const float* __restrict__ elt, const float* __restrict__ ert,
    float* __restrict__ out)
{
  __shared__ float er_s[N_];
  __shared__ float dpart[8][32][34];
  __shared__ float denp[8][32];

  const int t = threadIdx.x;
  const int u0 = blockIdx.x;
  const int v  = ((u0 & 7) << 7) | (u0 >> 3);   // XCD swizzle (1024 = 8*128)
  const int it   = v & 31;
  const int head = (v >> 5) & 7;
  const int b    = v >> 8;
  const int i0   = it * 32;
  const int hb   = b * NH + head;

  const int wv = t >> 6, lane = t & 63;
  const int li = lane & 15, kg = lane >> 4;

  if (t < 256) *(float4*)&er_s[4 * t] = *(const float4*)&ert[(size_t)hb * N_ + 4 * t];
  __syncthreads();

  const float el_a = elt[(size_t)hb * N_ + i0 + li];
  const float el_b = elt[(size_t)hb * N_ + i0 + 16 + li];
  const int4* __restrict__ abA =
      (const int4*)(adjb + ((size_t)(b * N_ + i0 + li)) * 32) + wv;
  const int4* __restrict__ abB =
      (const int4*)(adjb + ((size_t)(b * N_ + i0 + 16 + li)) * 32) + wv;
  const _Float16* __restrict__ arow0 =
      g16 + ((size_t)hb * ND + li) * N_ + wv * 128 + kg * 8;
  const _Float16* __restrict__ arow1 = arow0 + (size_t)16 * N_;

  f32x4 acc0 = {0,0,0,0}, acc1 = {0,0,0,0}, accd = {0,0,0,0};
  f32x4 acc0b = {0,0,0,0}, acc1b = {0,0,0,0}, accdb = {0,0,0,0};
  const half8 ones = {(_Float16)1.f, (_Float16)1.f, (_Float16)1.f, (_Float16)1.f,
                      (_Float16)1.f, (_Float16)1.f, (_Float16)1.f, (_Float16)1.f};

  const int4 A = abA[0];
  const int4 Bm = abB[0];
  const unsigned wA[4] = {(unsigned)A.x, (unsigned)A.y, (unsigned)A.z, (unsigned)A.w};
  const unsigned wB[4] = {(unsigned)Bm.x, (unsigned)Bm.y, (unsigned)Bm.z, (unsigned)Bm.w};

#pragma unroll
  for (int u = 0; u < 4; ++u) {
    const half8 Ag0 = *(const half8*)(arow0 + u * 32);
    const half8 Ag1 = *(const half8*)(arow1 + u * 32);
    const int ks = wv * 128 + u * 32 + kg * 8;
    const float4 e0 = *(const float4*)&er_s[ks];
    const float4 e1 = *(const float4*)&er_s[ks + 4];
    const float er8[8] = {e0.x, e0.y, e0.z, e0.w, e1.x, e1.y, e1.z, e1.w};
    const unsigned sA = wA[u] >> (kg * 8);
    const unsigned sB = wB[u] >> (kg * 8);

    float pva[8], pvb[8];
#pragma unroll
    for (int e = 0; e < 8; ++e) {
      float xa = el_a + er8[e];
      float xb = el_b + er8[e];
      xa = fmaxf(xa, NSL * xa);
      xb = fmaxf(xb, NSL * xb);
      float pa, pb;
      asm("v_exp_f32 %0, %1" : "=v"(pa) : "v"(xa));
      asm("v_exp_f32 %0, %1" : "=v"(pb) : "v"(xb));
      pva[e] = ((sA >> e) & 1u) ? pa : 0.f;
      pvb[e] = ((sB >> e) & 1u) ? pb : 0.f;
    }

    union { half8 h8; unsigned uu[4]; } PA, PB;
#pragma unroll
    for (int q = 0; q < 4; ++q) {
      union { fp16x2 hh; unsigned uu; } c1, c2;
      c1.hh = __builtin_amdgcn_cvt_pkrtz(pva[2*q], pva[2*q+1]);
      c2.hh = __builtin_amdgcn_cvt_pkrtz(pvb[2*q], pvb[2*q+1]);
      PA.uu[q] = c1.uu; PB.uu[q] = c2.uu;
    }

    acc0  = __builtin_amdgcn_mfma_f32_16x16x32_f16(Ag0, PA.h8, acc0, 0, 0, 0);
    acc1  = __builtin_amdgcn_mfma_f32_16x16x32_f16(Ag1, PA.h8, acc1, 0, 0, 0);
    accd  = __builtin_amdgcn_mfma_f32_16x16x32_f16(ones, PA.h8, accd, 0, 0, 0);
    acc0b = __builtin_amdgcn_mfma_f32_16x16x32_f16(Ag0, PB.h8, acc0b, 0, 0, 0);
    acc1b = __builtin_amdgcn_mfma_f32_16x16x32_f16(Ag1, PB.h8, acc1b, 0, 0, 0);
    accdb = __builtin_amdgcn_mfma_f32_16x16x32_f16(ones, PB.h8, accdb, 0, 0, 0);
  }

#pragma unroll
  for (int r = 0; r < 4; ++r) {
    dpart[wv][4*kg + r][li]           = acc0[r];
    dpart[wv][16 + 4*kg + r][li]      = acc1[r];
    dpart[wv][4*kg + r][16 + li]      = acc0b[r];
    dpart[wv][16 + 4*kg + r][16 + li] = acc1b[r];
  }
  if (lane < 16) { denp[wv][li] = accd[0]; denp[wv][16 + li] = accdb[0]; }
  __syncthreads();

  for (int o = t; o < 1024; o += 512) {
    const int f = o & 31, ii = o >> 5;
    float s = 0.f, dn = 0.f;
#pragma unroll
    for (int p = 0; p < 8; ++p) { s += dpart[p][f][ii]; dn += denp[p][ii]; }
    float w = s / dn;
    w = fmaxf(w, NSL * w);
    out[((size_t)(b * N_ + i0 + ii)) * FOUT + head * ND + f] = w;
  }
}

extern "C" void kernel_launch(void* const* d_in, const int* in_sizes, int n_in,
                              void* d_out, int out_size, void* d_ws, size_t ws_size,
                              hipStream_t stream) {
  const float* h     = (const float*)d_in[0];
  const int*   adj   = (const int*)d_in[1];
  const float* W     = (const float*)d_in[2];
  const float* a_vec = (const float*)d_in[3];
  float* out = (float*)d_out;

  char* ws = (char*)d_ws;
  _Float16* g16  = (_Float16*)(ws);                       // 2 MB
  float*    elt  = (float*)(ws + (2u << 20));             // 128 KB
  float*    ert  = (float*)(ws + (2u << 20) + (128u << 10));
  unsigned long long* adjb64 = (unsigned long long*)(ws + (2304u << 10)); // 512 KB
  _Float16* wt16 = (_Float16*)(ws + (2816u << 10));       // 64 KB

  gat_kA<<<1040, 256, 0, stream>>>(adj, adjb64, W, wt16);
  gat_kB<<<1024, 256, 0, stream>>>(h, wt16, a_vec, g16, elt, ert);
  gat_kC<<<1024, 512, 0, stream>>>((const unsigned*)adjb64, g16, elt, ert, out);
}